// Round 10
// baseline (264.018 us; speedup 1.0000x reference)
//
#include <hip/hip_runtime.h>
#include <math.h>

#define N_ 4096
#define D_ 768
#define P_ 100
#define PPAD 128
#define NROWS (N_ + PPAD)       /* 4224 staged rows */
#define NT 24                   /* K-tiles: 768 / 32 */
#define NTRI 528                /* lower-tri 128x128 tile pairs incl diag */
#define NBLK 560                /* 528 + 32 center tiles */
#define NWAVE (NBLK * 4)        /* 2240 waves */

typedef __attribute__((ext_vector_type(8))) short short8;
typedef __attribute__((ext_vector_type(4))) float f32x4;

typedef const __attribute__((address_space(1))) void* gld_src_t;
typedef __attribute__((address_space(3))) void* gld_dst_t;
#define GLOAD16(g, d) __builtin_amdgcn_global_load_lds((gld_src_t)(g), (gld_dst_t)(d), 16, 0, 0)

#define WAITVM4() asm volatile("s_waitcnt vmcnt(4)" ::: "memory")
#define WAITVM0() asm volatile("s_waitcnt vmcnt(0)" ::: "memory")
static __device__ __forceinline__ void barrier_fenced() {
    asm volatile("" ::: "memory");
    __builtin_amdgcn_s_barrier();
    asm volatile("" ::: "memory");
}

// manual grid barrier: legal because all 560 blocks are co-resident
// (launch_bounds(256,3) + 48KB LDS -> 3 blocks/CU -> 768 slots >= 560).
static __device__ __forceinline__ void grid_barrier(int* cnt, int target) {
    __syncthreads();                       // drains each thread's mem ops
    if (threadIdx.x == 0) {
        __threadfence();                   // release: L2 writeback (device scope)
        atomicAdd(cnt, 1);                 // device-scope arrival [m20]
        while (__hip_atomic_load(cnt, __ATOMIC_ACQUIRE,
                                 __HIP_MEMORY_SCOPE_AGENT) < target)
            __builtin_amdgcn_s_sleep(8);
    }
    __syncthreads();
    __threadfence();                       // acquire: invalidate stale lines
}

// float -> bf16 (RNE)
__device__ inline unsigned short f2bf(float f) {
    union { float f; unsigned int u; } v; v.f = f;
    unsigned int u = v.u + 0x7fffu + ((v.u >> 16) & 1u);
    return (unsigned short)(u >> 16);
}

// ---------------------------------------------------------------------------
// tile decode: orig -> XCD chunk (orig%8), slot k (0..69). k<66: triangular
// tile from region-ordered index (L2-local per XCD); k>=66: center tile.
static __device__ __forceinline__ void decode_tile(int orig, int* pit, int* pjt) {
    const int x = orig & 7;
    const int k = orig >> 3;
    if (k >= 66) { *pit = x * 4 + (k - 66); *pjt = 32; return; }
    const int g = x * 66 + k;
    const int cumR[11] = {0, 36, 100, 136, 200, 264, 300, 364, 428, 492, 528};
    const int GIr[10] = {0, 1, 1, 2, 2, 2, 3, 3, 3, 3};
    const int GJr[10] = {0, 0, 1, 0, 1, 2, 0, 1, 2, 3};
    int r = 0;
    while (cumR[r + 1] <= g) ++r;
    const int u = g - cumR[r];
    int di, dj;
    if (GIr[r] == GJr[r]) {
        di = 0;
        while ((di + 1) * (di + 2) / 2 <= u) ++di;
        dj = u - di * (di + 1) / 2;
    } else {
        di = u >> 3; dj = u & 7;
    }
    *pit = GIr[r] * 8 + di;
    *pjt = GJr[r] * 8 + dj;
}

// ===========================================================================
// ONE kernel: pre -> barrier -> mfma -> barrier -> combine -> last-block final.
__global__ __launch_bounds__(256, 3) void fused_kernel(
    const float* __restrict__ X, const int* __restrict__ T,
    const float* __restrict__ C, float* __restrict__ out,
    float* __restrict__ sq, float* __restrict__ csq,
    float* __restrict__ minc, float* __restrict__ bsum,
    unsigned short* __restrict__ Xbf, unsigned short* __restrict__ cnbf,
    float* __restrict__ ap_part, float* __restrict__ an_part,
    int* __restrict__ sync) {
    __shared__ __align__(16) unsigned short lds[3 * 8192];   // 48 KB

    const int tid = threadIdx.x;
    const int l = tid & 63;
    const int w = tid >> 6;       // wave 0..3

    // ================= phase 1: pre (bf16 cast, norms) ====================
    {
        const int wid0 = blockIdx.x * 4 + w;
        for (int gw = wid0; gw < NROWS; gw += NWAVE) {
            if (gw < N_) {
                const float4* x4 = (const float4*)(X + (size_t)gw * D_);
                short4* ob = (short4*)(Xbf + (size_t)gw * D_);
                float s = 0.f;
#pragma unroll
                for (int c = 0; c < 3; ++c) {
                    float4 v = x4[c * 64 + l];
                    s = fmaf(v.x, v.x, fmaf(v.y, v.y, fmaf(v.z, v.z, fmaf(v.w, v.w, s))));
                    short4 o;
                    o.x = (short)f2bf(v.x); o.y = (short)f2bf(v.y);
                    o.z = (short)f2bf(v.z); o.w = (short)f2bf(v.w);
                    ob[c * 64 + l] = o;
                }
#pragma unroll
                for (int m = 1; m < 64; m <<= 1) s += __shfl_xor(s, m);
                if (l == 0) sq[gw] = s;
            } else {
                const int p = gw - N_;
                short4* ob = (short4*)(cnbf + (size_t)p * D_);
                if (p < P_) {
                    const float4* c4 = (const float4*)(C + (size_t)p * D_);
                    float4 v[3];
                    float s = 0.f;
#pragma unroll
                    for (int c = 0; c < 3; ++c) {
                        v[c] = c4[c * 64 + l];
                        s = fmaf(v[c].x, v[c].x, fmaf(v[c].y, v[c].y,
                            fmaf(v[c].z, v[c].z, fmaf(v[c].w, v[c].w, s))));
                    }
#pragma unroll
                    for (int m = 1; m < 64; m <<= 1) s += __shfl_xor(s, m);
                    float rn = 1.0f / sqrtf(s);
#pragma unroll
                    for (int c = 0; c < 3; ++c) {
                        short4 o;
                        o.x = (short)f2bf(v[c].x * rn); o.y = (short)f2bf(v[c].y * rn);
                        o.z = (short)f2bf(v[c].z * rn); o.w = (short)f2bf(v[c].w * rn);
                        ob[c * 64 + l] = o;
                    }
                    if (l == 0) csq[p] = s * rn * rn;
                } else {
                    short4 z; z.x = z.y = z.z = z.w = 0;
#pragma unroll
                    for (int c = 0; c < 3; ++c) ob[c * 64 + l] = z;
                    if (l == 0) csq[p] = 1e30f;
                }
            }
        }
    }
    grid_barrier(&sync[0], NBLK);

    // ================= phase 2: mfma tiles (R6 structure) =================
    {
        const int wr = w >> 1;
        const int wc = w & 1;
        int it, jt;
        decode_tile(blockIdx.x, &it, &jt);
        const bool is_center = (jt == 32);
        const int i0 = it * 128;
        const int j0 = is_center ? 0 : jt * 128;
        const unsigned short* __restrict__ Bmat = is_center ? cnbf : Xbf;

        const int srow = tid >> 2;
        const int scol = ((tid & 3) * 8) ^ (((srow & 6) >> 1) << 3);
        const unsigned short* gA0 = Xbf + (size_t)(i0 + srow) * D_ + scol;
        const unsigned short* gA1 = gA0 + (size_t)64 * D_;
        const unsigned short* gB0 = Bmat + (size_t)(j0 + srow) * D_ + scol;
        const unsigned short* gB1 = gB0 + (size_t)64 * D_;
        const int dA0 = w * 512, dA1 = 2048 + w * 512;
        const int dB0 = 4096 + w * 512, dB1 = 6144 + w * 512;

        const int col = l & 15;
        const int hi = l >> 4;
        const int rko = (hi * 8) ^ ((l & 6) << 2);
        const int aro = (wr * 64 + col) * 32 + rko;
        const int bro = 4096 + (wc * 64 + col) * 32 + rko;

        f32x4 acc[4][4];
#pragma unroll
        for (int m = 0; m < 4; ++m)
#pragma unroll
            for (int n = 0; n < 4; ++n) acc[m][n] = (f32x4){0.f, 0.f, 0.f, 0.f};

#define STAGE(t)                                                     \
    do {                                                             \
        const int bo_ = ((t) % 3) * 8192;                            \
        const int ke_ = (t) * 32;                                    \
        GLOAD16(gA0 + ke_, &lds[bo_ + dA0]);                         \
        GLOAD16(gA1 + ke_, &lds[bo_ + dA1]);                         \
        GLOAD16(gB0 + ke_, &lds[bo_ + dB0]);                         \
        GLOAD16(gB1 + ke_, &lds[bo_ + dB1]);                         \
    } while (0)

        STAGE(0);
        STAGE(1);
        WAITVM4();
        barrier_fenced();

        int bo = 0;
        for (int t = 0; t < NT; ++t) {
            if (t + 2 < NT) STAGE(t + 2);
            const unsigned short* Lb = &lds[bo * 8192];
            short8 a[4], b[4];
#pragma unroll
            for (int m = 0; m < 4; ++m)
                a[m] = *reinterpret_cast<const short8*>(Lb + aro + m * 512);
#pragma unroll
            for (int n = 0; n < 4; ++n)
                b[n] = *reinterpret_cast<const short8*>(Lb + bro + n * 512);
#pragma unroll
            for (int m = 0; m < 4; ++m)
#pragma unroll
                for (int n = 0; n < 4; ++n)
                    acc[m][n] = __builtin_amdgcn_mfma_f32_16x16x32_bf16(
                        a[m], b[n], acc[m][n], 0, 0, 0);
            if (t < NT - 1) {
                if (t + 2 < NT) WAITVM4();
                else WAITVM0();
                barrier_fenced();
            }
            bo = (bo == 2) ? 0 : bo + 1;
        }
#undef STAGE

        // ---- epilogue: fused distances + dual-side reductions ----
        float* lf = (float*)lds;
        __syncthreads();

        if (!is_center) {
            float sqj[4]; int tj[4];
#pragma unroll
            for (int n = 0; n < 4; ++n) {
                int j = j0 + wc * 64 + n * 16 + col;
                sqj[n] = sq[j];
                tj[n] = T[j];
            }
            float apC[4], anC[4];
#pragma unroll
            for (int n = 0; n < 4; ++n) { apC[n] = -1e30f; anC[n] = 1e30f; }

#pragma unroll
            for (int m = 0; m < 4; ++m) {
#pragma unroll
                for (int r = 0; r < 4; ++r) {
                    const int lrow = wr * 64 + m * 16 + hi * 4 + r;
                    const int i = i0 + lrow;
                    float sqi = sq[i];
                    int ti = T[i];
                    float apR = -1e30f, anR = 1e30f;
#pragma unroll
                    for (int n = 0; n < 4; ++n) {
                        float d2 = sqi + sqj[n] - 2.0f * acc[m][n][r];
                        float d = sqrtf(fmaxf(d2, 1e-12f));
                        bool same = (tj[n] == ti);
                        apR = same ? fmaxf(apR, d) : apR;
                        anR = same ? anR : fminf(anR, d);
                        apC[n] = same ? fmaxf(apC[n], d) : apC[n];
                        anC[n] = same ? anC[n] : fminf(anC[n], d);
                    }
#pragma unroll
                    for (int msk = 1; msk < 16; msk <<= 1) {
                        apR = fmaxf(apR, __shfl_xor(apR, msk));
                        anR = fminf(anR, __shfl_xor(anR, msk));
                    }
                    if (col == 0) {
                        lf[wc * 128 + lrow] = apR;
                        lf[256 + wc * 128 + lrow] = anR;
                    }
                }
            }
            __syncthreads();
            if (tid < 128) {
                float a = fmaxf(lf[tid], lf[128 + tid]);
                float b = fminf(lf[256 + tid], lf[384 + tid]);
                ap_part[(size_t)jt * N_ + i0 + tid] = a;
                an_part[(size_t)jt * N_ + i0 + tid] = b;
            }

            if (it != jt) {
                __syncthreads();
#pragma unroll
                for (int n = 0; n < 4; ++n) {
                    apC[n] = fmaxf(apC[n], __shfl_xor(apC[n], 16));
                    apC[n] = fmaxf(apC[n], __shfl_xor(apC[n], 32));
                    anC[n] = fminf(anC[n], __shfl_xor(anC[n], 16));
                    anC[n] = fminf(anC[n], __shfl_xor(anC[n], 32));
                    if (hi == 0) {
                        int jl = wc * 64 + n * 16 + col;
                        lf[wr * 128 + jl] = apC[n];
                        lf[256 + wr * 128 + jl] = anC[n];
                    }
                }
                __syncthreads();
                if (tid < 128) {
                    float a = fmaxf(lf[tid], lf[128 + tid]);
                    float b = fminf(lf[256 + tid], lf[384 + tid]);
                    ap_part[(size_t)(32 + it) * N_ + j0 + tid] = a;
                    an_part[(size_t)(32 + it) * N_ + j0 + tid] = b;
                }
            }
        } else {
            float sqj[4];
#pragma unroll
            for (int n = 0; n < 4; ++n) sqj[n] = csq[wc * 64 + n * 16 + col];
#pragma unroll
            for (int m = 0; m < 4; ++m) {
#pragma unroll
                for (int r = 0; r < 4; ++r) {
                    const int lrow = wr * 64 + m * 16 + hi * 4 + r;
                    const int i = i0 + lrow;
                    float sqi = sq[i];
                    float mc = 1e30f;
#pragma unroll
                    for (int n = 0; n < 4; ++n) {
                        float d2 = sqi + sqj[n] - 2.0f * acc[m][n][r];
                        float d = fmaxf(sqrtf(fmaxf(d2, 0.0f)), 1e-12f);
                        mc = fminf(mc, d);
                    }
#pragma unroll
                    for (int msk = 1; msk < 16; msk <<= 1)
                        mc = fminf(mc, __shfl_xor(mc, msk));
                    if (col == 0) lf[wc * 128 + lrow] = mc;
                }
            }
            __syncthreads();
            if (tid < 128) minc[i0 + tid] = fminf(lf[tid], lf[128 + tid]);
        }
    }
    grid_barrier(&sync[16], NBLK);

    // ================= phase 3: combine (wave-parallel over slots) ========
    {
        float* sred = (float*)lds;
        const int wid0 = blockIdx.x * 4 + w;
        const int l2 = l & 31;
        float wsum = 0.f;
        for (int i = wid0; i < N_; i += NWAVE) {
            const int r = i >> 7;
            const int s = (l2 <= r) ? l2 : 32 + l2;
            float v = (l < 32) ? ap_part[(size_t)s * N_ + i]
                               : an_part[(size_t)s * N_ + i];
#pragma unroll
            for (int m = 1; m < 32; m <<= 1) {
                float o = __shfl_xor(v, m);
                v = (l < 32) ? fmaxf(v, o) : fminf(v, o);
            }
            float ap = __shfl(v, 0);
            float an = __shfl(v, 32);
            float dan = (an < 1e29f) ? an : (ap + 1.0f);
            dan = fminf(dan, minc[i]);
            wsum += fmaxf(0.0f, 1.0f + ap - dan);
        }
        if (l == 0) sred[w] = wsum;
        __syncthreads();
        if (tid == 0)
            bsum[blockIdx.x] = sred[0] + sred[1] + sred[2] + sred[3];
    }

    // ================= phase 4: last-block finalize =======================
    {
        __shared__ int amlast;
        if (tid == 0) {
            __threadfence();                       // publish bsum
            amlast = (atomicAdd(&sync[32], 1) == NBLK - 1);
        }
        __syncthreads();
        if (amlast) {
            __threadfence();                       // acquire all bsum
            float* sred = (float*)lds;
            float s = bsum[tid];
            if (tid + 256 < NBLK) s += bsum[tid + 256];
            if (tid + 512 < NBLK) s += bsum[tid + 512];
#pragma unroll
            for (int m = 32; m > 0; m >>= 1) s += __shfl_xor(s, m);
            if (l == 0) sred[64 + w] = s;
            __syncthreads();
            if (tid == 0)
                out[0] = (sred[64] + sred[65] + sred[66] + sred[67]) / (float)N_;
        }
    }
}

// ---------------------------------------------------------------------------
// Workspace layout (floats; audited):
//   sq      : [0,        4096)
//   csq     : [4096,     4224)
//   minc    : [4224,     8320)
//   bsum    : [8320,     8880)   (560)
//   Xbf     : [8880,     1581744)  4096*768 ushorts = 1,572,864 floats
//   cnbf    : [1581744,  1630896)  128*768 ushorts  =    49,152 floats
//   ap_part : [1630896,  1893040)  64*4096
//   an_part : [1893040,  2155184)  64*4096
//   sync    : [2155184,  2155232)  3 counters at 64B spacing (memset each call)
extern "C" void kernel_launch(void* const* d_in, const int* in_sizes, int n_in,
                              void* d_out, int out_size, void* d_ws, size_t ws_size,
                              hipStream_t stream) {
    const float* X = (const float*)d_in[0];
    const int* T = (const int*)d_in[1];
    const float* C = (const float*)d_in[2];
    float* out = (float*)d_out;

    float* ws = (float*)d_ws;
    float* sq = ws;
    float* csq = ws + 4096;
    float* minc = ws + 4224;
    float* bsum = ws + 8320;
    unsigned short* Xbf = (unsigned short*)(ws + 8880);
    unsigned short* cnbf = (unsigned short*)(ws + 1581744);
    float* ap_part = ws + 1630896;
    float* an_part = ws + 1893040;
    int* sync = (int*)(ws + 2155184);

    hipMemsetAsync(sync, 0, 192, stream);   // reset barrier counters every call
    fused_kernel<<<NBLK, 256, 0, stream>>>(X, T, C, out, sq, csq, minc, bsum,
                                           Xbf, cnbf, ap_part, an_part, sync);
}

// Round 11
// 50.783 us; speedup vs baseline: 5.1989x; 5.1989x over previous
//
#include <hip/hip_runtime.h>
#include <math.h>

#define N_ 4096
#define D_ 768
#define P_ 100
#define PPAD 128
#define NT 24                   /* K-tiles: 768 / 32 */
#define NTRI 528                /* lower-tri 128x128 tile pairs incl diag */
#define NBLK 560                /* 528 + 32 center tiles */

typedef __attribute__((ext_vector_type(8))) short short8;
typedef __attribute__((ext_vector_type(4))) float f32x4;

typedef const __attribute__((address_space(1))) void* gld_src_t;
typedef __attribute__((address_space(3))) void* gld_dst_t;
#define GLOAD16(g, d) __builtin_amdgcn_global_load_lds((gld_src_t)(g), (gld_dst_t)(d), 16, 0, 0)

#define WAITVM4() asm volatile("s_waitcnt vmcnt(4)" ::: "memory")
#define WAITVM0() asm volatile("s_waitcnt vmcnt(0)" ::: "memory")
#define WAITLGKM0() asm volatile("s_waitcnt lgkmcnt(0)" ::: "memory")

// float -> bf16 (RNE)
__device__ inline unsigned short f2bf(float f) {
    union { float f; unsigned int u; } v; v.f = f;
    unsigned int u = v.u + 0x7fffu + ((v.u >> 16) & 1u);
    return (unsigned short)(u >> 16);
}

// ---------------------------------------------------------------------------
// tile decode: orig -> XCD chunk (orig%8), slot k (0..69). k<66: triangular
// tile from region-ordered index (L2-local per XCD); k>=66: center tile.
static __device__ __forceinline__ void decode_tile(int orig, int* pit, int* pjt) {
    const int x = orig & 7;
    const int k = orig >> 3;
    if (k >= 66) { *pit = x * 4 + (k - 66); *pjt = 32; return; }
    const int g = x * 66 + k;
    const int cumR[11] = {0, 36, 100, 136, 200, 264, 300, 364, 428, 492, 528};
    const int GIr[10] = {0, 1, 1, 2, 2, 2, 3, 3, 3, 3};
    const int GJr[10] = {0, 0, 1, 0, 1, 2, 0, 1, 2, 3};
    int r = 0;
    while (cumR[r + 1] <= g) ++r;
    const int u = g - cumR[r];
    int di, dj;
    if (GIr[r] == GJr[r]) {
        di = 0;
        while ((di + 1) * (di + 2) / 2 <= u) ++di;
        dj = u - di * (di + 1) / 2;
    } else {
        di = u >> 3; dj = u & 7;
    }
    *pit = GIr[r] * 8 + di;
    *pjt = GJr[r] * 8 + dj;
}

// ---------------------------------------------------------------------------
__global__ __launch_bounds__(256) void pre_kernel(
    const float* __restrict__ X, const float* __restrict__ C,
    float* __restrict__ sq, unsigned short* __restrict__ Xbf,
    unsigned short* __restrict__ cnbf, float* __restrict__ csq) {
    const int gw = blockIdx.x * 4 + (threadIdx.x >> 6);
    const int l = threadIdx.x & 63;
    if (gw < N_) {
        const float4* x4 = (const float4*)(X + (size_t)gw * D_);
        short4* ob = (short4*)(Xbf + (size_t)gw * D_);
        float s = 0.f;
#pragma unroll
        for (int c = 0; c < 3; ++c) {
            float4 v = x4[c * 64 + l];
            s = fmaf(v.x, v.x, fmaf(v.y, v.y, fmaf(v.z, v.z, fmaf(v.w, v.w, s))));
            short4 o;
            o.x = (short)f2bf(v.x); o.y = (short)f2bf(v.y);
            o.z = (short)f2bf(v.z); o.w = (short)f2bf(v.w);
            ob[c * 64 + l] = o;
        }
#pragma unroll
        for (int m = 1; m < 64; m <<= 1) s += __shfl_xor(s, m);
        if (l == 0) sq[gw] = s;
    } else {
        const int p = gw - N_;
        if (p >= PPAD) return;
        short4* ob = (short4*)(cnbf + (size_t)p * D_);
        if (p < P_) {
            const float4* c4 = (const float4*)(C + (size_t)p * D_);
            float4 v[3];
            float s = 0.f;
#pragma unroll
            for (int c = 0; c < 3; ++c) {
                v[c] = c4[c * 64 + l];
                s = fmaf(v[c].x, v[c].x, fmaf(v[c].y, v[c].y,
                    fmaf(v[c].z, v[c].z, fmaf(v[c].w, v[c].w, s))));
            }
#pragma unroll
            for (int m = 1; m < 64; m <<= 1) s += __shfl_xor(s, m);
            float rn = 1.0f / sqrtf(s);
#pragma unroll
            for (int c = 0; c < 3; ++c) {
                short4 o;
                o.x = (short)f2bf(v[c].x * rn); o.y = (short)f2bf(v[c].y * rn);
                o.z = (short)f2bf(v[c].z * rn); o.w = (short)f2bf(v[c].w * rn);
                ob[c * 64 + l] = o;
            }
            if (l == 0) csq[p] = s * rn * rn;
        } else {
            short4 z; z.x = z.y = z.z = z.w = 0;
#pragma unroll
            for (int c = 0; c < 3; ++c) ob[c * 64 + l] = z;
            if (l == 0) csq[p] = 1e30f;
        }
    }
}

// ---------------------------------------------------------------------------
// MFMA kernel: 128x128 tile, BK=32, 3-buffer ring, counted vmcnt(4).
// CHAIN-SHORTENED schedule: per step { ds_read frags; STAGE(t+2); lgkm0;
// vmcnt(4); barrier; sched_barrier; MFMA }  -- MFMAs execute AFTER the
// barrier, overlapping the next step's ds_read latency. Correct because the
// barrier only orders LDS buffer reuse, and reads are complete (lgkm0).
__global__ __launch_bounds__(256, 3) void mfma_kernel(
    const unsigned short* __restrict__ Xbf, const unsigned short* __restrict__ cnbf,
    const int* __restrict__ T, const float* __restrict__ sq,
    const float* __restrict__ csq,
    float* __restrict__ ap_part, float* __restrict__ an_part,
    float* __restrict__ minc) {
    __shared__ __align__(16) unsigned short lds[3 * 8192];   // 48 KB

    const int tid = threadIdx.x;
    const int l = tid & 63;
    const int w = tid >> 6;
    const int wr = w >> 1;
    const int wc = w & 1;

    int it, jt;
    decode_tile(blockIdx.x, &it, &jt);
    const bool is_center = (jt == 32);
    const int i0 = it * 128;
    const int j0 = is_center ? 0 : jt * 128;
    const unsigned short* __restrict__ Bmat = is_center ? cnbf : Xbf;

    const int srow = tid >> 2;
    const int scol = ((tid & 3) * 8) ^ (((srow & 6) >> 1) << 3);
    const unsigned short* gA0 = Xbf + (size_t)(i0 + srow) * D_ + scol;
    const unsigned short* gA1 = gA0 + (size_t)64 * D_;
    const unsigned short* gB0 = Bmat + (size_t)(j0 + srow) * D_ + scol;
    const unsigned short* gB1 = gB0 + (size_t)64 * D_;
    const int dA0 = w * 512, dA1 = 2048 + w * 512;
    const int dB0 = 4096 + w * 512, dB1 = 6144 + w * 512;

    const int col = l & 15;
    const int hi = l >> 4;
    const int rko = (hi * 8) ^ ((l & 6) << 2);
    const int aro = (wr * 64 + col) * 32 + rko;
    const int bro = 4096 + (wc * 64 + col) * 32 + rko;

    f32x4 acc[4][4];
#pragma unroll
    for (int m = 0; m < 4; ++m)
#pragma unroll
        for (int n = 0; n < 4; ++n) acc[m][n] = (f32x4){0.f, 0.f, 0.f, 0.f};

#define STAGE(t)                                                     \
    do {                                                             \
        const int bo_ = ((t) % 3) * 8192;                            \
        const int ke_ = (t) * 32;                                    \
        GLOAD16(gA0 + ke_, &lds[bo_ + dA0]);                         \
        GLOAD16(gA1 + ke_, &lds[bo_ + dA1]);                         \
        GLOAD16(gB0 + ke_, &lds[bo_ + dB0]);                         \
        GLOAD16(gB1 + ke_, &lds[bo_ + dB1]);                         \
    } while (0)

    STAGE(0);
    STAGE(1);
    WAITVM4();                       // buf0 landed; buf1's 4 still in flight
    __builtin_amdgcn_s_barrier();
    __builtin_amdgcn_sched_barrier(0);

    int bo = 0;
#pragma unroll 3
    for (int t = 0; t < NT; ++t) {
        const unsigned short* Lb = &lds[bo * 8192];
        short8 a[4], b[4];
#pragma unroll
        for (int m = 0; m < 4; ++m)
            a[m] = *reinterpret_cast<const short8*>(Lb + aro + m * 512);
#pragma unroll
        for (int n = 0; n < 4; ++n)
            b[n] = *reinterpret_cast<const short8*>(Lb + bro + n * 512);
        if (t + 2 < NT) STAGE(t + 2);
        WAITLGKM0();                 // my reads of buf[bo] complete
        if (t < NT - 1) {
            if (t + 2 < NT) WAITVM4();   // next buf landed; 4 stay in flight
            else WAITVM0();              // tail drain
            __builtin_amdgcn_s_barrier();
            __builtin_amdgcn_sched_barrier(0);
        }
        // MFMAs AFTER the barrier: overlap next step's ds_read latency
#pragma unroll
        for (int m = 0; m < 4; ++m)
#pragma unroll
            for (int n = 0; n < 4; ++n)
                acc[m][n] = __builtin_amdgcn_mfma_f32_16x16x32_bf16(
                    a[m], b[n], acc[m][n], 0, 0, 0);
        bo = (bo == 2) ? 0 : bo + 1;
    }
#undef STAGE

    // ---------------- epilogue -------------------------------------------
    // C/D layout: col = lane&15, row = (lane>>4)*4 + reg
    float* lf = (float*)lds;
    __syncthreads();

    if (!is_center) {
        float sqj[4]; int tj[4];
#pragma unroll
        for (int n = 0; n < 4; ++n) {
            int j = j0 + wc * 64 + n * 16 + col;
            sqj[n] = sq[j];
            tj[n] = T[j];
        }
        float apC[4], anC[4];
#pragma unroll
        for (int n = 0; n < 4; ++n) { apC[n] = -1e30f; anC[n] = 1e30f; }

#pragma unroll
        for (int m = 0; m < 4; ++m) {
#pragma unroll
            for (int r = 0; r < 4; ++r) {
                const int lrow = wr * 64 + m * 16 + hi * 4 + r;
                const int i = i0 + lrow;
                float sqi = sq[i];
                int ti = T[i];
                float apR = -1e30f, anR = 1e30f;
#pragma unroll
                for (int n = 0; n < 4; ++n) {
                    float d2 = sqi + sqj[n] - 2.0f * acc[m][n][r];
                    float d = sqrtf(fmaxf(d2, 1e-12f));
                    bool same = (tj[n] == ti);
                    apR = same ? fmaxf(apR, d) : apR;
                    anR = same ? anR : fminf(anR, d);
                    apC[n] = same ? fmaxf(apC[n], d) : apC[n];
                    anC[n] = same ? anC[n] : fminf(anC[n], d);
                }
#pragma unroll
                for (int msk = 1; msk < 16; msk <<= 1) {
                    apR = fmaxf(apR, __shfl_xor(apR, msk));
                    anR = fminf(anR, __shfl_xor(anR, msk));
                }
                if (col == 0) {
                    lf[wc * 128 + lrow] = apR;
                    lf[256 + wc * 128 + lrow] = anR;
                }
            }
        }
        __syncthreads();
        if (tid < 128) {
            float a = fmaxf(lf[tid], lf[128 + tid]);
            float b = fminf(lf[256 + tid], lf[384 + tid]);
            ap_part[(size_t)jt * N_ + i0 + tid] = a;
            an_part[(size_t)jt * N_ + i0 + tid] = b;
        }

        if (it != jt) {
            __syncthreads();
#pragma unroll
            for (int n = 0; n < 4; ++n) {
                apC[n] = fmaxf(apC[n], __shfl_xor(apC[n], 16));
                apC[n] = fmaxf(apC[n], __shfl_xor(apC[n], 32));
                anC[n] = fminf(anC[n], __shfl_xor(anC[n], 16));
                anC[n] = fminf(anC[n], __shfl_xor(anC[n], 32));
                if (hi == 0) {
                    int jl = wc * 64 + n * 16 + col;
                    lf[wr * 128 + jl] = apC[n];
                    lf[256 + wr * 128 + jl] = anC[n];
                }
            }
            __syncthreads();
            if (tid < 128) {
                float a = fmaxf(lf[tid], lf[128 + tid]);
                float b = fminf(lf[256 + tid], lf[384 + tid]);
                ap_part[(size_t)(32 + it) * N_ + j0 + tid] = a;
                an_part[(size_t)(32 + it) * N_ + j0 + tid] = b;
            }
        }
    } else {
        float sqj[4];
#pragma unroll
        for (int n = 0; n < 4; ++n) sqj[n] = csq[wc * 64 + n * 16 + col];
#pragma unroll
        for (int m = 0; m < 4; ++m) {
#pragma unroll
            for (int r = 0; r < 4; ++r) {
                const int lrow = wr * 64 + m * 16 + hi * 4 + r;
                const int i = i0 + lrow;
                float sqi = sq[i];
                float mc = 1e30f;
#pragma unroll
                for (int n = 0; n < 4; ++n) {
                    float d2 = sqi + sqj[n] - 2.0f * acc[m][n][r];
                    float d = fmaxf(sqrtf(fmaxf(d2, 0.0f)), 1e-12f);
                    mc = fminf(mc, d);
                }
#pragma unroll
                for (int msk = 1; msk < 16; msk <<= 1)
                    mc = fminf(mc, __shfl_xor(mc, msk));
                if (col == 0) lf[wc * 128 + lrow] = mc;
            }
        }
        __syncthreads();
        if (tid < 128) minc[i0 + tid] = fminf(lf[tid], lf[128 + tid]);
    }
}

// ---------------------------------------------------------------------------
// combine: wave-parallel. One wave per 4 rows; lane l2=l&31 owns one slot:
// row-side jt=l2 (if l2<=r) else col-side 32+l2. Lanes 0-31 carry ap (max),
// lanes 32-63 carry an (min); 5-step shuffle reduce within each half.
__global__ __launch_bounds__(256) void combine2(
    const float* __restrict__ ap_part, const float* __restrict__ an_part,
    const float* __restrict__ minc, float* __restrict__ bsum) {
    const int w = threadIdx.x >> 6;
    const int l = threadIdx.x & 63;
    const int l2 = l & 31;
    float wsum = 0.f;
#pragma unroll
    for (int q = 0; q < 4; ++q) {
        const int i = blockIdx.x * 16 + w * 4 + q;
        const int r = i >> 7;
        const int s = (l2 <= r) ? l2 : 32 + l2;
        float v = (l < 32) ? ap_part[(size_t)s * N_ + i]
                           : an_part[(size_t)s * N_ + i];
#pragma unroll
        for (int m = 1; m < 32; m <<= 1) {
            float o = __shfl_xor(v, m);
            v = (l < 32) ? fmaxf(v, o) : fminf(v, o);
        }
        float ap = __shfl(v, 0);
        float an = __shfl(v, 32);
        float dan = (an < 1e29f) ? an : (ap + 1.0f);
        dan = fminf(dan, minc[i]);
        wsum += fmaxf(0.0f, 1.0f + ap - dan);
    }
    if (l == 0) bsum[blockIdx.x * 4 + w] = wsum;
}

__global__ __launch_bounds__(256) void finalize(
    const float* __restrict__ bsum, float* __restrict__ out) {
    __shared__ float sred[4];
    const int tid = threadIdx.x;
    float s = bsum[tid] + bsum[tid + 256] + bsum[tid + 512] + bsum[tid + 768];
#pragma unroll
    for (int m = 32; m > 0; m >>= 1) s += __shfl_xor(s, m);
    if ((tid & 63) == 0) sred[tid >> 6] = s;
    __syncthreads();
    if (tid == 0)
        out[0] = (sred[0] + sred[1] + sred[2] + sred[3]) / (float)N_;
}

// ---------------------------------------------------------------------------
// Workspace layout (floats; audited):
//   sq      : [0,        4096)
//   csq     : [4096,     4224)
//   minc    : [4224,     8320)
//   bsum    : [8320,     9344)   (1024)
//   Xbf     : [9344,     1582208)  4096*768 ushorts = 1,572,864 floats
//   cnbf    : [1582208,  1631360)  128*768 ushorts  =    49,152 floats
//   ap_part : [1631360,  1893504)  64*4096
//   an_part : [1893504,  2155648)  64*4096   (~8.62 MB total)
extern "C" void kernel_launch(void* const* d_in, const int* in_sizes, int n_in,
                              void* d_out, int out_size, void* d_ws, size_t ws_size,
                              hipStream_t stream) {
    const float* X = (const float*)d_in[0];
    const int* T = (const int*)d_in[1];
    const float* C = (const float*)d_in[2];
    float* out = (float*)d_out;

    float* ws = (float*)d_ws;
    float* sq = ws;
    float* csq = ws + 4096;
    float* minc = ws + 4224;
    float* bsum = ws + 8320;
    unsigned short* Xbf = (unsigned short*)(ws + 9344);
    unsigned short* cnbf = (unsigned short*)(ws + 1582208);
    float* ap_part = ws + 1631360;
    float* an_part = ws + 1893504;

    pre_kernel<<<(N_ + PPAD) / 4, 256, 0, stream>>>(X, C, sq, Xbf, cnbf, csq);
    mfma_kernel<<<NBLK, 256, 0, stream>>>(Xbf, cnbf, T, sq, csq, ap_part, an_part, minc);
    combine2<<<N_ / 16, 256, 0, stream>>>(ap_part, an_part, minc, bsum);
    finalize<<<1, 256, 0, stream>>>(bsum, out);
}